// Round 3
// baseline (10135.059 us; speedup 1.0000x reference)
//
#include <hip/hip_runtime.h>
#include <hip/hip_bf16.h>
#include <math.h>

// T=128, B=32, D=512, H=512, N=64, A=32, TAU=1
#define NTHR    512
#define NBLK    176            // 32 BC blocks + 144 GEMM blocks
#define NGEMM   144
#define HTXS    19456          // hTx buffer stride in floats (18432 + 4KB pad)

// ---- workspace layout (float offsets) ----
#define OFF_HTX   256                       // hTx_all: [129][32][576] (stride HTXS)
#define OFF_OC    (OFF_HTX + 129*HTXS)      // oc: [32][4608]
#define OFF_HNEW  (OFF_OC + 32*4608)        // hnew_part: [32][64][512]
#define OFF_WHH   (OFF_HNEW + 32*64*512)    // whh_part: [32][64][1536]
#define OFF_C0    (OFF_WHH + 32*64*1536)    // c0: [1536]
#define OFF_WCATT (OFF_C0 + 1536)           // WcatT: [4608][576] col-major weights
#define OFF_MTMP  (OFF_WCATT + 4608*576)    // scratch [512][1536]
#define OFF_P1    (OFF_MTMP + 512*1536)     // P1: [4096][1536]
#define OFF_P2    (OFF_P1 + 4096*1536)      // P2: [4096][512]
// end = OFF_P2 + 4096*512 = 18,682,624 floats = 74.7 MB (< 76.5 MB known-good)

// sc1 (agent-scope) ops: bypass per-XCD L2, coherent at memory-side LLC.
__device__ __forceinline__ float cohLoad(const float* p) {
  return __hip_atomic_load(p, __ATOMIC_RELAXED, __HIP_MEMORY_SCOPE_AGENT);
}
__device__ __forceinline__ void cohStore(float* p, float v) {
  __hip_atomic_store(p, v, __ATOMIC_RELAXED, __HIP_MEMORY_SCOPE_AGENT);
}
__device__ __forceinline__ void bar_arrive(int* cnt) {
  __syncthreads();   // drains vmcnt: all sc1 stores complete before the add
  if (threadIdx.x == 0)
    __hip_atomic_fetch_add(cnt, 1, __ATOMIC_RELAXED, __HIP_MEMORY_SCOPE_AGENT);
}
__device__ __forceinline__ void bar_wait(int* cnt, int target) {
  if (threadIdx.x == 0) {
    while (__hip_atomic_load(cnt, __ATOMIC_RELAXED, __HIP_MEMORY_SCOPE_AGENT) < target)
      __builtin_amdgcn_s_sleep(1);
  }
  __syncthreads();
}

// ---------------------------------------------------------------------------
// Generic tiled fp32 GEMM (pre-pass only): C[M,N] = A[M,K]@B[K,N] (+bias)
// ---------------------------------------------------------------------------
__global__ __launch_bounds__(256) void gemm_f32(
    const float* __restrict__ A, const float* __restrict__ B,
    const float* __restrict__ bias, float* __restrict__ C,
    int M, int N, int K, int lda, int ldb, int ldc)
{
  __shared__ float As[16][132];
  __shared__ float Bs[16][64];
  const int bm = blockIdx.x * 128, bn = blockIdx.y * 64;
  const int tid = threadIdx.x;
  const int tx = tid & 15, ty = tid >> 4;
  float acc[8][4];
  #pragma unroll
  for (int i = 0; i < 8; ++i)
    #pragma unroll
    for (int j = 0; j < 4; ++j) acc[i][j] = 0.f;

  for (int kt = 0; kt < K; kt += 16) {
    #pragma unroll
    for (int i = 0; i < 2; ++i) {
      int li = tid + i*256;
      int r = li >> 2, q = li & 3;
      float4 a4 = *(const float4*)(A + (size_t)(bm + r)*lda + kt + q*4);
      As[q*4+0][r] = a4.x; As[q*4+1][r] = a4.y;
      As[q*4+2][r] = a4.z; As[q*4+3][r] = a4.w;
    }
    {
      int k = tid >> 4, nq = tid & 15;
      *(float4*)(&Bs[k][nq*4]) = *(const float4*)(B + (size_t)(kt + k)*ldb + bn + nq*4);
    }
    __syncthreads();
    #pragma unroll
    for (int kk = 0; kk < 16; ++kk) {
      float av[8], bv[4];
      *(float4*)(av)   = *(const float4*)(&As[kk][ty*8]);
      *(float4*)(av+4) = *(const float4*)(&As[kk][ty*8+4]);
      *(float4*)(bv)   = *(const float4*)(&Bs[kk][tx*4]);
      #pragma unroll
      for (int i = 0; i < 8; ++i)
        #pragma unroll
        for (int j = 0; j < 4; ++j) acc[i][j] += av[i]*bv[j];
    }
    __syncthreads();
  }
  #pragma unroll
  for (int i = 0; i < 8; ++i) {
    int m = bm + ty*8 + i;
    #pragma unroll
    for (int j = 0; j < 4; ++j) {
      int n = bn + tx*4 + j;
      float v = acc[i][j];
      if (bias) v += bias[n];
      C[(size_t)m*ldc + n] = v;
    }
  }
}

// ---------------------------------------------------------------------------
// Setup: WcatT static parts (col-major [c][k]) + c0.
// cols: [0:512)=W_hm/W_um  [512:1024)=fc2_A  [1024:1536)=fc2_B
//       [1536:4608) zero-filled here, overwritten by GEMM+transpose.
// ---------------------------------------------------------------------------
__global__ __launch_bounds__(512) void setup_kernel(
    const float* __restrict__ W_hm, const float* __restrict__ fc2_w,
    const float* __restrict__ W_um, const float* __restrict__ W_hh,
    const float* __restrict__ bias, const float* __restrict__ fc2_b,
    float* __restrict__ WcatT, float* __restrict__ c0)
{
  const int idx = blockIdx.x * 512 + threadIdx.x;
  if (idx < 4608*576) {
    int c = idx / 576, k = idx % 576;
    float v = 0.f;
    if (c < 512)       v = (k < 512) ? W_hm[k*512 + c] : W_um[(k-512)*512 + c];
    else if (c < 1024) v = (k < 512) ? fc2_w[k*512 + (c-512)] : 0.f;
    else if (c < 1536) v = (k < 512) ? fc2_w[(size_t)(512+k)*512 + (c-1024)] : 0.f;
    WcatT[idx] = v;
    return;
  }
  int i = idx - 4608*576;
  if (i < 1536) {                             // c0 = fc2_b@W_hh + bias_hh
    float s = bias[1536 + i];
    for (int m = 0; m < 512; ++m) s += fc2_b[m] * W_hh[(size_t)m*1536 + i];
    c0[i] = s;
  }
}

// dst[j][k] (ld 576) = Mtmp[k][j],  j<1536, k<512
__global__ __launch_bounds__(512) void trans_kernel(
    const float* __restrict__ Mtmp, float* __restrict__ dst)
{
  const int idx = blockIdx.x * 512 + threadIdx.x;   // 1536*512
  const int j = idx >> 9, k = idx & 511;
  dst[(size_t)j*576 + k] = Mtmp[(size_t)k*1536 + j];
}

// ---------------------------------------------------------------------------
// Persistent scan. Blocks 0..31: BC (batch b). Blocks 32..175: GEMM (32 cols).
// GEMM: full-K (576) dots, hx staged in LDS from rotating hTx buffer (normal
// cached reads, first-touch fresh). Results -> oc via sc1. BC: th/logits/
// argmax/gates in-block, state in registers, writes next hTx buffer via sc1.
// ---------------------------------------------------------------------------
__global__ __launch_bounds__(NTHR, 1) void persist_kernel(
    const float* __restrict__ P1, const float* __restrict__ P2,
    const float* __restrict__ WcatT, float* __restrict__ oc,
    float* __restrict__ hTx_all, float* __restrict__ hnew_part,
    float* __restrict__ whh_part, const float* __restrict__ c0,
    const float* __restrict__ fc1_w, const float* __restrict__ fc1_b,
    const float* __restrict__ fc2_b, const float* __restrict__ u_noise,
    const int* __restrict__ length, const float* __restrict__ fc_w,
    const float* __restrict__ fc_b, float* __restrict__ out,
    int* __restrict__ bar)
{
  __shared__ float smem[18432];    // GEMM: hx[32][576]; BC: th/lg/lsc/flags
  const int bid = blockIdx.x;
  const int tid = threadIdx.x;
  int* cnt1 = bar;                 // GEMM arrivals (144/step)
  int* cnt2 = bar + 64;            // BC arrivals (32/step), separate line

  if (bid >= 32) {
    // ---------------- GEMM block: cols [c0g, c0g+32) ----------------------
    const int c0g = (bid - 32) * 32;
    const int c2  = (tid & 15) * 2;          // 2 adjacent cols per thread
    const int bb  = tid >> 4;                // batch 0..31
    const float* w0 = WcatT + (size_t)(c0g + c2) * 576;
    const float* w1 = w0 + 576;
    float* oc0 = oc + (size_t)bb*4608 + c0g + c2;

    for (int t = 0; t < 128; ++t) {
      // stage hx (32*576 floats) into LDS — normal cached loads
      const float* hsrc = hTx_all + (size_t)t * HTXS;
      for (int i = tid; i < 4608; i += NTHR)
        *(float4*)(smem + i*4) = *(const float4*)(hsrc + i*4);
      __syncthreads();

      const float* hb = smem + bb*576;
      float a0 = 0.f, a1 = 0.f;
      #pragma unroll 4
      for (int k = 0; k < 576; k += 4) {
        float4 h4 = *(const float4*)(hb + k);
        float4 wa = *(const float4*)(w0 + k);
        float4 wb = *(const float4*)(w1 + k);
        a0 += wa.x*h4.x + wa.y*h4.y + wa.z*h4.z + wa.w*h4.w;
        a1 += wb.x*h4.x + wb.y*h4.y + wb.z*h4.z + wb.w*h4.w;
      }
      cohStore(oc0, a0);
      cohStore(oc0 + 1, a1);
      bar_arrive(cnt1);
      bar_wait(cnt2, (t + 1) * 32);          // wait for BC to finish step t
    }
  } else {
    // ---------------- BC block: batch b ----------------------------------
    const int b = bid;
    const int lenb = length[b];
    float hcur = 0.f;                        // h[tid], persists in register
    float usage_r = -99999.f;                // usage[tid] for tid<64
    int jprev = 0;                           // thread-0 register
    int* flg = (int*)(smem + 1088);

    for (int t = 0; t < 128; ++t) {
      bar_wait(cnt1, (t + 1) * NGEMM);
      const float* ocb = oc + (size_t)b*4608;
      const int t32b = t*32 + b;
      // th = tanh(P2 + oc[:512])
      smem[tid] = tanhf(P2[(size_t)t32b*512 + tid] + cohLoad(&ocb[tid]));
      __syncthreads();
      // logits partials: n = tid&63, kg = tid>>6
      {
        int n = tid & 63, kg = tid >> 6;
        float s = 0.f;
        const float* fw = fc1_w + (size_t)kg*64*64 + n;
        #pragma unroll 8
        for (int k = 0; k < 64; ++k) s += smem[kg*64 + k] * fw[(size_t)k*64];
        smem[512 + tid] = s;
      }
      __syncthreads();
      if (tid < 64) {
        float l = fc1_b[tid];
        #pragma unroll
        for (int kg = 0; kg < 8; ++kg) l += smem[512 + kg*64 + tid];
        float u = u_noise[(size_t)t32b*64 + tid];
        l += -logf(1e-20f - logf(1e-20f + u));     // Gumbel
        smem[1024 + tid] = l;
      }
      __syncthreads();
      if (tid == 0) {
        int jj = 0; float best = smem[1024];
        for (int n2 = 1; n2 < 64; ++n2)
          if (smem[1024 + n2] > best) { best = smem[1024 + n2]; jj = n2; }
        flg[0] = jj;
        flg[1] = (t < 64) ? t : jprev;       // write slot
        jprev = jj;
      }
      __syncthreads();
      const int jj = flg[0], ss = flg[1];
      // segment sums (single full-K values now)
      const int j = tid;
      float vA   = cohLoad(&ocb[ 512 + j]);
      float vB   = cohLoad(&ocb[1024 + j]);
      float vAW0 = cohLoad(&ocb[1536 + j]);
      float vAW1 = cohLoad(&ocb[2048 + j]);
      float vAW2 = cohLoad(&ocb[2560 + j]);
      float vBW0 = cohLoad(&ocb[3072 + j]);
      float vBW1 = cohLoad(&ocb[3584 + j]);
      float vBW2 = cohLoad(&ocb[4096 + j]);
      float hnp, w0, w1, w2;
      if (jj == ss) { hnp = vA; w0 = vAW0; w1 = vAW1; w2 = vAW2; }
      else {
        hnp = hnew_part[(size_t)(b*64 + jj)*512 + j];
        const float* wpp = whh_part + (size_t)(b*64 + jj)*1536;
        w0 = wpp[j]; w1 = wpp[512 + j]; w2 = wpp[1024 + j];
      }
      float h_new = hnp + vB + fc2_b[j];
      float wh_r = w0 + vBW0 + c0[j];
      float wh_z = w1 + vBW1 + c0[512 + j];
      float wh_n = w2 + vBW2 + c0[1024 + j];
      const float* p1 = P1 + (size_t)t32b*1536;
      float r  = 1.f / (1.f + expf(-(p1[j]       + wh_r)));
      float z  = 1.f / (1.f + expf(-(p1[512 + j] + wh_z)));
      float nn = tanhf(p1[1024 + j] + r*wh_n);
      float h1 = (1.f - z)*nn + z*h_new;
      if (t >= lenb) h1 = hcur;
      hcur = h1;
      // slot caches (block-private, normal cached)
      hnew_part[(size_t)(b*64 + ss)*512 + j] = vA;
      float* wps = whh_part + (size_t)(b*64 + ss)*1536;
      wps[j] = vAW0; wps[512 + j] = vAW1; wps[1024 + j] = vAW2;
      // h -> next hTx buffer (sc1)
      float* hw = hTx_all + (size_t)(t + 1)*HTXS + (size_t)b*576;
      cohStore(&hw[j], h1);
      __syncthreads();                       // th reads done; reuse smem
      smem[j] = h1;
      if (tid < 64) {
        float un = (usage_r - 1.f) * (tid == jj ? 0.f : 1.f);
        usage_r = un;
        cohStore(&hw[512 + tid], 1.f / (1.f + expf(-un)));   // lu
      }
      __syncthreads();
      // out[t32b] = h1 @ fc_w + fc_b  (fused final projection)
      {
        int a = tid & 31, jg = tid >> 5;
        float s = 0.f;
        #pragma unroll 8
        for (int jx = 0; jx < 32; ++jx)
          s += smem[jg*32 + jx] * fc_w[(size_t)(jg*32 + jx)*32 + a];
        smem[512 + tid] = s;
      }
      __syncthreads();
      if (tid < 32) {
        float s = fc_b[tid];
        #pragma unroll
        for (int jg = 0; jg < 16; ++jg) s += smem[512 + jg*32 + tid];
        out[(size_t)t32b*32 + tid] = s;
      }
      bar_arrive(cnt2);
    }
  }
}

// ---------------------------------------------------------------------------
extern "C" void kernel_launch(void* const* d_in, const int* in_sizes, int n_in,
                              void* d_out, int out_size, void* d_ws, size_t ws_size,
                              hipStream_t stream)
{
  const float* x      = (const float*)d_in[0];
  const int*   length = (const int*)  d_in[1];
  const float* u_nois = (const float*)d_in[2];
  const float* W_ih   = (const float*)d_in[3];
  const float* W_hh   = (const float*)d_in[4];
  const float* bias   = (const float*)d_in[5];
  const float* W_im   = (const float*)d_in[6];
  const float* W_hm   = (const float*)d_in[7];
  const float* W_um   = (const float*)d_in[8];
  const float* fc1_w  = (const float*)d_in[9];
  const float* fc1_b  = (const float*)d_in[10];
  const float* fc2_w  = (const float*)d_in[11];
  const float* fc2_b  = (const float*)d_in[12];
  const float* fc_w   = (const float*)d_in[13];
  const float* fc_b   = (const float*)d_in[14];
  float* out = (float*)d_out;

  float* ws    = (float*)d_ws;
  int*   bar   = (int*)d_ws;
  float* hTx   = ws + OFF_HTX;
  float* oc    = ws + OFF_OC;
  float* hnew  = ws + OFF_HNEW;
  float* whh   = ws + OFF_WHH;
  float* c0    = ws + OFF_C0;
  float* WcatT = ws + OFF_WCATT;
  float* Mtmp  = ws + OFF_MTMP;
  float* P1    = ws + OFF_P1;
  float* P2    = ws + OFF_P2;

  // zero: barriers + hTx buffer 0 (h=0, lu=0) ; slot caches (mem=0)
  hipMemsetAsync(d_ws, 0, (size_t)(OFF_HTX + HTXS) * sizeof(float), stream);
  hipMemsetAsync(hnew, 0, (size_t)(32*64*512 + 32*64*1536) * sizeof(float), stream);

  setup_kernel<<<5188, 512, 0, stream>>>(W_hm, fc2_w, W_um, W_hh, bias, fc2_b,
                                         WcatT, c0);

  // M_A = fc2_A@W_hh -> WcatT cols 1536:3072 ; M_B -> cols 3072:4608
  { dim3 g(4, 24);
    gemm_f32<<<g, 256, 0, stream>>>(fc2_w, W_hh, nullptr, Mtmp,
                                    512, 1536, 512, 512, 1536, 1536);
    trans_kernel<<<1536, 512, 0, stream>>>(Mtmp, WcatT + (size_t)1536*576);
    gemm_f32<<<g, 256, 0, stream>>>(fc2_w + 512*512, W_hh, nullptr, Mtmp,
                                    512, 1536, 512, 512, 1536, 1536);
    trans_kernel<<<1536, 512, 0, stream>>>(Mtmp, WcatT + (size_t)3072*576); }
  // P1 = x@W_ih + bias_ih ; P2 = x@W_im
  { dim3 g(32, 24);
    gemm_f32<<<g, 256, 0, stream>>>(x, W_ih, bias, P1, 4096, 1536, 512, 512, 1536, 1536); }
  { dim3 g(32, 8);
    gemm_f32<<<g, 256, 0, stream>>>(x, W_im, nullptr, P2, 4096, 512, 512, 512, 512, 512); }

  persist_kernel<<<NBLK, NTHR, 0, stream>>>(P1, P2, WcatT, oc, hTx, hnew, whh,
                                            c0, fc1_w, fc1_b, fc2_b, u_nois,
                                            length, fc_w, fc_b, out, bar);
}

// Round 4
// 2685.556 us; speedup vs baseline: 3.7739x; 3.7739x over previous
//
#include <hip/hip_runtime.h>
#include <hip/hip_bf16.h>
#include <math.h>

// T=128, B=32, D=512, H=512, N=64, A=32, TAU=1
#define NTHR  512
#define NBLK  176              // 32 BC blocks + 144 GEMM blocks
#define NGEMM 144
#define HTXS  19456            // hTx buffer stride (18432 + pad)

// ---- workspace layout (float offsets) ----
#define OFF_HTX  256                        // hTx_all: [129][576][32] k-major
#define OFF_OC   (OFF_HTX + 129*HTXS)       // oc: [32][4608]
#define OFF_HNEW (OFF_OC + 32*4608)         // hnew_part: [32][64][512]
#define OFF_WHH  (OFF_HNEW + 32*64*512)     // whh_part: [32][64][1536]
#define OFF_C0   (OFF_WHH + 32*64*1536)     // c0: [1536]
#define OFF_WCAT (OFF_C0 + 1536)            // Wcat: [576][4608] row-major
#define OFF_P1   (OFF_WCAT + 576*4608)      // P1: [4096][1536]
#define OFF_P2   (OFF_P1 + 4096*1536)       // P2: [4096][512]
// end = OFF_P2 + 4096*512 = 17,896,192 floats = 71.6 MB

// sc1 (agent-scope) ops: bypass per-XCD L2, coherent at LLC.
__device__ __forceinline__ float cohLoad(const float* p) {
  return __hip_atomic_load(p, __ATOMIC_RELAXED, __HIP_MEMORY_SCOPE_AGENT);
}
__device__ __forceinline__ void cohStore(float* p, float v) {
  __hip_atomic_store(p, v, __ATOMIC_RELAXED, __HIP_MEMORY_SCOPE_AGENT);
}
__device__ __forceinline__ int cohLoadI(const int* p) {
  return __hip_atomic_load(p, __ATOMIC_RELAXED, __HIP_MEMORY_SCOPE_AGENT);
}

// ---------------------------------------------------------------------------
// Generic tiled fp32 GEMM (pre-pass only)
// ---------------------------------------------------------------------------
__global__ __launch_bounds__(256) void gemm_f32(
    const float* __restrict__ A, const float* __restrict__ B,
    const float* __restrict__ bias, float* __restrict__ C,
    int M, int N, int K, int lda, int ldb, int ldc)
{
  __shared__ float As[16][132];
  __shared__ float Bs[16][64];
  const int bm = blockIdx.x * 128, bn = blockIdx.y * 64;
  const int tid = threadIdx.x;
  const int tx = tid & 15, ty = tid >> 4;
  float acc[8][4];
  #pragma unroll
  for (int i = 0; i < 8; ++i)
    #pragma unroll
    for (int j = 0; j < 4; ++j) acc[i][j] = 0.f;

  for (int kt = 0; kt < K; kt += 16) {
    #pragma unroll
    for (int i = 0; i < 2; ++i) {
      int li = tid + i*256;
      int r = li >> 2, q = li & 3;
      float4 a4 = *(const float4*)(A + (size_t)(bm + r)*lda + kt + q*4);
      As[q*4+0][r] = a4.x; As[q*4+1][r] = a4.y;
      As[q*4+2][r] = a4.z; As[q*4+3][r] = a4.w;
    }
    {
      int k = tid >> 4, nq = tid & 15;
      *(float4*)(&Bs[k][nq*4]) = *(const float4*)(B + (size_t)(kt + k)*ldb + bn + nq*4);
    }
    __syncthreads();
    #pragma unroll
    for (int kk = 0; kk < 16; ++kk) {
      float av[8], bv[4];
      *(float4*)(av)   = *(const float4*)(&As[kk][ty*8]);
      *(float4*)(av+4) = *(const float4*)(&As[kk][ty*8+4]);
      *(float4*)(bv)   = *(const float4*)(&Bs[kk][tx*4]);
      #pragma unroll
      for (int i = 0; i < 8; ++i)
        #pragma unroll
        for (int j = 0; j < 4; ++j) acc[i][j] += av[i]*bv[j];
    }
    __syncthreads();
  }
  #pragma unroll
  for (int i = 0; i < 8; ++i) {
    int m = bm + ty*8 + i;
    #pragma unroll
    for (int j = 0; j < 4; ++j) {
      int n = bn + tx*4 + j;
      float v = acc[i][j];
      if (bias) v += bias[n];
      C[(size_t)m*ldc + n] = v;
    }
  }
}

// ---------------------------------------------------------------------------
// Setup: Wcat (row-major [576][4608]) static parts + c0.
// cols [0:512)=W_hm (rows<512) / W_um (rows 512:576); [512:1024)=fc2_A;
// [1024:1536)=fc2_B; [1536:4608) filled by M_A/M_B GEMMs (rows 512:576 = 0).
// ---------------------------------------------------------------------------
__global__ __launch_bounds__(512) void setup_kernel(
    const float* __restrict__ W_hm, const float* __restrict__ fc2_w,
    const float* __restrict__ W_um, const float* __restrict__ W_hh,
    const float* __restrict__ bias, const float* __restrict__ fc2_b,
    float* __restrict__ Wcat, float* __restrict__ c0)
{
  const int idx = blockIdx.x * 512 + threadIdx.x;
  if (idx < 512*1536) {                       // rows 0:512, cols 0:1536
    int k = idx / 1536, c = idx % 1536;
    float v;
    if (c < 512)       v = W_hm[k*512 + c];
    else if (c < 1024) v = fc2_w[k*512 + (c-512)];
    else               v = fc2_w[(size_t)(512+k)*512 + (c-1024)];
    Wcat[(size_t)k*4608 + c] = v;
    return;
  }
  int i = idx - 512*1536;
  if (i < 64*4608) {                          // rows 512:576, all cols
    int k2 = i / 4608, c = i % 4608;
    Wcat[(size_t)(512+k2)*4608 + c] = (c < 512) ? W_um[k2*512 + c] : 0.f;
    return;
  }
  i -= 64*4608;
  if (i < 1536) {                             // c0 = fc2_b@W_hh + bias_hh
    float s = bias[1536 + i];
    for (int m = 0; m < 512; ++m) s += fc2_b[m] * W_hh[(size_t)m*1536 + i];
    c0[i] = s;
  }
}

// ---------------------------------------------------------------------------
// Persistent scan. Blocks 0..31: BC (batch). Blocks 32..175: GEMM (32 cols).
// GEMM thread tile: 4 batches x 8 cols, 16 K-segments of 36; shuffle+LDS
// reduce. Barrier: 4 arrival counters (36 each) -> BC; 1 counter (32) -> GEMM.
// ---------------------------------------------------------------------------
__global__ __launch_bounds__(NTHR, 1) void persist_kernel(
    const float* __restrict__ P1, const float* __restrict__ P2,
    const float* __restrict__ Wcat, float* __restrict__ oc,
    float* __restrict__ hTx_all, float* __restrict__ hnew_part,
    float* __restrict__ whh_part, const float* __restrict__ c0,
    const float* __restrict__ fc1_w, const float* __restrict__ fc1_b,
    const float* __restrict__ fc2_b, const float* __restrict__ u_noise,
    const int* __restrict__ length, const float* __restrict__ fc_w,
    const float* __restrict__ fc_b, float* __restrict__ out,
    int* __restrict__ bar)
{
  __shared__ float smem[27648];    // GEMM: hxs[18432] + red[9216]; BC: scratch
  const int bid = blockIdx.x;
  const int tid = threadIdx.x;
  int* cntA = bar;                 // 4 lines: bar[0],bar[32],bar[64],bar[96]
  int* cntB = bar + 128;

  if (bid >= 32) {
    // ================= GEMM block =================
    const int gb  = bid - 32;
    const int c0g = gb * 32;
    const int g   = gb & 3;
    const int s   = tid >> 5;            // K-segment 0..15 (36 k each)
    const int tile= tid & 31;
    const int co  = tile & 3;            // col-oct 0..3 (8 cols)
    const int bq  = tile >> 2;           // batch-quad 0..7
    const int wv  = tid >> 6;            // wave id 0..7
    const int kbase = s * 36;
    float* hxs = smem;
    float* red = smem + 18432;           // [8 waves][32 b][36 (32c+pad)]

    for (int t = 0; t < 128; ++t) {
      // wait until h(t) published (t=0 trivially true)
      if (tid == 0) {
        while (cohLoadI(cntB) < t*32) __builtin_amdgcn_s_sleep(1);
      }
      __syncthreads();
      // stage hx[576][32] into LDS
      const float* hsrc = hTx_all + (size_t)t * HTXS;
      for (int i = tid; i < 4608; i += NTHR)
        *(float4*)(hxs + i*4) = *(const float4*)(hsrc + i*4);
      __syncthreads();
      // register-tiled outer product
      float acc[4][8];
      #pragma unroll
      for (int bi = 0; bi < 4; ++bi)
        #pragma unroll
        for (int cj = 0; cj < 8; ++cj) acc[bi][cj] = 0.f;
      const float* wp = Wcat + (size_t)kbase*4608 + c0g + co*8;
      const float* hp = hxs + kbase*32 + bq*4;
      #pragma unroll 4
      for (int kk = 0; kk < 36; ++kk) {
        float4 h4 = *(const float4*)(hp); hp += 32;
        float4 wa = *(const float4*)(wp);
        float4 wb = *(const float4*)(wp + 4); wp += 4608;
        float hv[4] = {h4.x, h4.y, h4.z, h4.w};
        float wvv[8] = {wa.x, wa.y, wa.z, wa.w, wb.x, wb.y, wb.z, wb.w};
        #pragma unroll
        for (int bi = 0; bi < 4; ++bi)
          #pragma unroll
          for (int cj = 0; cj < 8; ++cj) acc[bi][cj] += hv[bi] * wvv[cj];
      }
      // reduce across the wave's two K-halves (lane ^ 32)
      #pragma unroll
      for (int bi = 0; bi < 4; ++bi)
        #pragma unroll
        for (int cj = 0; cj < 8; ++cj)
          acc[bi][cj] += __shfl_xor(acc[bi][cj], 32);
      if ((tid & 32) == 0) {               // low half writes wave partial
        float* rp = red + wv*1152 + (bq*4)*36 + co*8;
        #pragma unroll
        for (int bi = 0; bi < 4; ++bi) {
          *(float4*)(rp + bi*36)     = make_float4(acc[bi][0], acc[bi][1], acc[bi][2], acc[bi][3]);
          *(float4*)(rp + bi*36 + 4) = make_float4(acc[bi][4], acc[bi][5], acc[bi][6], acc[bi][7]);
        }
      }
      __syncthreads();
      // final 8-way reduce + sc1 store to oc
      {
        int o = tid * 2;
        int b = o >> 5, c = o & 31;
        const float* rp = red + b*36 + c;
        float s0 = 0.f, s1 = 0.f;
        #pragma unroll
        for (int w = 0; w < 8; ++w) { s0 += rp[w*1152]; s1 += rp[w*1152 + 1]; }
        float* op = oc + (size_t)b*4608 + c0g + c;
        cohStore(op, s0); cohStore(op + 1, s1);
      }
      __syncthreads();                     // drain sc1 stores
      if (tid == 0)
        __hip_atomic_fetch_add(&cntA[g*32], 1, __ATOMIC_RELAXED, __HIP_MEMORY_SCOPE_AGENT);
    }
  } else {
    // ================= BC block: batch b =================
    const int b = bid;
    const int lenb = length[b];
    float hcur = 0.f;
    float usage_r = -99999.f;              // valid for tid<64
    int jprev = 0;                         // thread-0 only
    int* flg = (int*)(smem + 1100);
    // hoisted constants
    const float c0r = c0[tid], c0z = c0[512 + tid], c0n = c0[1024 + tid];
    const float fc2bv = fc2_b[tid];
    const float f1b = (tid < 64) ? fc1_b[tid] : 0.f;
    const int n_ = tid & 63, kg_ = tid >> 6;
    const float* fw = fc1_w + (size_t)kg_*64*64 + n_;

    for (int t = 0; t < 128; ++t) {
      const int t32b = t*32 + b;
      // prefetch step inputs (independent of barrier)
      const float* p1p = P1 + (size_t)t32b*1536;
      float p1r = p1p[tid], p1z = p1p[512 + tid], p1n = p1p[1024 + tid];
      float p2v = P2[(size_t)t32b*512 + tid];
      float uval = (tid < 64) ? u_noise[(size_t)t32b*64 + tid] : 0.f;
      // wait for all 144 GEMM blocks (4 counter lines)
      if (tid == 0) {
        const int tgt = (t + 1) * 36;
        while (cohLoadI(&cntA[0])  < tgt || cohLoadI(&cntA[32]) < tgt ||
               cohLoadI(&cntA[64]) < tgt || cohLoadI(&cntA[96]) < tgt)
          __builtin_amdgcn_s_sleep(1);
      }
      __syncthreads();
      const float* ocb = oc + (size_t)b*4608;
      // issue all oc loads up front
      float oct  = cohLoad(ocb + tid);
      float vA   = cohLoad(ocb + 512  + tid);
      float vB   = cohLoad(ocb + 1024 + tid);
      float vAW0 = cohLoad(ocb + 1536 + tid);
      float vAW1 = cohLoad(ocb + 2048 + tid);
      float vAW2 = cohLoad(ocb + 2560 + tid);
      float vBW0 = cohLoad(ocb + 3072 + tid);
      float vBW1 = cohLoad(ocb + 3584 + tid);
      float vBW2 = cohLoad(ocb + 4096 + tid);
      smem[tid] = tanhf(p2v + oct);        // th
      __syncthreads();
      {                                    // fc1 partial dots
        float sdot = 0.f;
        #pragma unroll 8
        for (int k = 0; k < 64; ++k) sdot += smem[kg_*64 + k] * fw[(size_t)k*64];
        smem[512 + tid] = sdot;
      }
      __syncthreads();
      if (tid < 64) {                      // logits + Gumbel + wave argmax
        float l = f1b;
        #pragma unroll
        for (int kg = 0; kg < 8; ++kg) l += smem[512 + kg*64 + tid];
        l += -logf(1e-20f - logf(1e-20f + uval));
        float best = l; int idx = tid;
        #pragma unroll
        for (int off = 32; off >= 1; off >>= 1) {
          float ob = __shfl_xor(best, off);
          int   oi = __shfl_xor(idx,  off);
          if (ob > best || (ob == best && oi < idx)) { best = ob; idx = oi; }
        }
        if (tid == 0) {
          flg[0] = idx;
          flg[1] = (t < 64) ? t : jprev;
          jprev = idx;
        }
      }
      __syncthreads();
      const int jj = flg[0], ss = flg[1];
      // gates
      float hnp, w0, w1, w2;
      if (jj == ss) { hnp = vA; w0 = vAW0; w1 = vAW1; w2 = vAW2; }
      else {
        hnp = hnew_part[(size_t)(b*64 + jj)*512 + tid];
        const float* wpp = whh_part + (size_t)(b*64 + jj)*1536;
        w0 = wpp[tid]; w1 = wpp[512 + tid]; w2 = wpp[1024 + tid];
      }
      float h_new = hnp + vB + fc2bv;
      float wh_r = w0 + vBW0 + c0r;
      float wh_z = w1 + vBW1 + c0z;
      float wh_n = w2 + vBW2 + c0n;
      float r  = 1.f / (1.f + expf(-(p1r + wh_r)));
      float z  = 1.f / (1.f + expf(-(p1z + wh_z)));
      float nn = tanhf(p1n + r*wh_n);
      float h1 = (1.f - z)*nn + z*h_new;
      if (t >= lenb) h1 = hcur;
      hcur = h1;
      // publish h(t+1) + lu via sc1 (k-major layout [576][32])
      float* hw = hTx_all + (size_t)(t + 1)*HTXS;
      cohStore(&hw[tid*32 + b], h1);
      if (tid < 64) {
        float un = (usage_r - 1.f) * (tid == jj ? 0.f : 1.f);
        usage_r = un;
        cohStore(&hw[(512 + tid)*32 + b], 1.f / (1.f + expf(-un)));
      }
      smem[tid] = h1;                      // published by arrive's syncthreads
      // arrive (syncthreads drains sc1 stores, then counter bump)
      __syncthreads();
      if (tid == 0)
        __hip_atomic_fetch_add(cntB, 1, __ATOMIC_RELAXED, __HIP_MEMORY_SCOPE_AGENT);
      // ---- off critical path: slot caches + output projection ----
      hnew_part[(size_t)(b*64 + ss)*512 + tid] = vA;
      float* wps = whh_part + (size_t)(b*64 + ss)*1536;
      wps[tid] = vAW0; wps[512 + tid] = vAW1; wps[1024 + tid] = vAW2;
      {
        int a = tid & 31, jg = tid >> 5;
        float sp = 0.f;
        #pragma unroll 8
        for (int jx = 0; jx < 32; ++jx)
          sp += smem[jg*32 + jx] * fc_w[(size_t)(jg*32 + jx)*32 + a];
        smem[512 + tid] = sp;
      }
      __syncthreads();
      if (tid < 32) {
        float s2 = fc_b[tid];
        #pragma unroll
        for (int jg = 0; jg < 16; ++jg) s2 += smem[512 + jg*32 + tid];
        out[(size_t)t32b*32 + tid] = s2;
      }
    }
  }
}

// ---------------------------------------------------------------------------
extern "C" void kernel_launch(void* const* d_in, const int* in_sizes, int n_in,
                              void* d_out, int out_size, void* d_ws, size_t ws_size,
                              hipStream_t stream)
{
  const float* x      = (const float*)d_in[0];
  const int*   length = (const int*)  d_in[1];
  const float* u_nois = (const float*)d_in[2];
  const float* W_ih   = (const float*)d_in[3];
  const float* W_hh   = (const float*)d_in[4];
  const float* bias   = (const float*)d_in[5];
  const float* W_im   = (const float*)d_in[6];
  const float* W_hm   = (const float*)d_in[7];
  const float* W_um   = (const float*)d_in[8];
  const float* fc1_w  = (const float*)d_in[9];
  const float* fc1_b  = (const float*)d_in[10];
  const float* fc2_w  = (const float*)d_in[11];
  const float* fc2_b  = (const float*)d_in[12];
  const float* fc_w   = (const float*)d_in[13];
  const float* fc_b   = (const float*)d_in[14];
  float* out = (float*)d_out;

  float* ws   = (float*)d_ws;
  int*   bar  = (int*)d_ws;
  float* hTx  = ws + OFF_HTX;
  float* oc   = ws + OFF_OC;
  float* hnew = ws + OFF_HNEW;
  float* whh  = ws + OFF_WHH;
  float* c0   = ws + OFF_C0;
  float* Wcat = ws + OFF_WCAT;
  float* P1   = ws + OFF_P1;
  float* P2   = ws + OFF_P2;

  // zero: barrier counters + hTx buffer 0 (h=0, lu=0); slot caches (mem=0)
  hipMemsetAsync(d_ws, 0, (size_t)(OFF_HTX + HTXS) * sizeof(float), stream);
  hipMemsetAsync(hnew, 0, (size_t)(32*64*512 + 32*64*1536) * sizeof(float), stream);

  setup_kernel<<<2115, 512, 0, stream>>>(W_hm, fc2_w, W_um, W_hh, bias, fc2_b,
                                         Wcat, c0);

  // M_A = fc2_A@W_hh -> Wcat cols 1536:3072 ; M_B = fc2_B@W_hh -> 3072:4608
  { dim3 g(4, 24);
    gemm_f32<<<g, 256, 0, stream>>>(fc2_w,                  W_hh, nullptr, Wcat + 1536,
                                    512, 1536, 512, 512, 1536, 4608);
    gemm_f32<<<g, 256, 0, stream>>>(fc2_w + (size_t)512*512, W_hh, nullptr, Wcat + 3072,
                                    512, 1536, 512, 512, 1536, 4608); }
  // P1 = x@W_ih + bias_ih ; P2 = x@W_im
  { dim3 g(32, 24);
    gemm_f32<<<g, 256, 0, stream>>>(x, W_ih, bias, P1, 4096, 1536, 512, 512, 1536, 1536); }
  { dim3 g(32, 8);
    gemm_f32<<<g, 256, 0, stream>>>(x, W_im, nullptr, P2, 4096, 512, 512, 512, 512, 512); }

  persist_kernel<<<NBLK, NTHR, 0, stream>>>(P1, P2, Wcat, oc, hTx, hnew, whh,
                                            c0, fc1_w, fc1_b, fc2_b, u_nois,
                                            length, fc_w, fc_b, out, bar);
}

// Round 6
// 2480.924 us; speedup vs baseline: 4.0852x; 1.0825x over previous
//
#include <hip/hip_runtime.h>
#include <hip/hip_bf16.h>
#include <math.h>

// T=128, B=32, D=512, H=512, N=64, A=32, TAU=1
#define NTHR  512
#define NBLK  224              // 32 BC blocks + 192 GEMM blocks
#define NGEMM 192
#define HTXS  19456            // hTx buffer stride (18432 + pad)

// ---- workspace layout (float offsets). Barrier lines in first 512 floats. --
// barA: 8 lines at int offsets 0,32,..,224   (GEMM arrivals, 24/line/step)
// barB: 4 lines at int offsets 256,288,320,352 (BC arrivals, 8/line/step)
#define OFF_HTX  512                        // hTx_all: [129][576][32] k-major
#define OFF_OC   (OFF_HTX + 129*HTXS)       // oc: [32][4608]
#define OFF_HNEW (OFF_OC + 32*4608)         // hnew_part: [32][64][512]
#define OFF_WHH  (OFF_HNEW + 32*64*512)     // whh_part: [32][64][1536]
#define OFF_C0   (OFF_WHH + 32*64*1536)     // c0: [1536]
#define OFF_WCAT (OFF_C0 + 1536)            // Wcat: [576][4608] row-major
#define OFF_P1   (OFF_WCAT + 576*4608)      // P1: [4096][1536]
#define OFF_P2   (OFF_P1 + 4096*1536)       // P2: [4096][512]
// end = OFF_P2 + 4096*512 ≈ 71.6 MB

// sc1 (agent-scope) ops: bypass per-XCD L2, coherent at LLC.
__device__ __forceinline__ float cohLoad(const float* p) {
  return __hip_atomic_load(p, __ATOMIC_RELAXED, __HIP_MEMORY_SCOPE_AGENT);
}
__device__ __forceinline__ void cohStore(float* p, float v) {
  __hip_atomic_store(p, v, __ATOMIC_RELAXED, __HIP_MEMORY_SCOPE_AGENT);
}
__device__ __forceinline__ int cohLoadI(const int* p) {
  return __hip_atomic_load(p, __ATOMIC_RELAXED, __HIP_MEMORY_SCOPE_AGENT);
}

// ---------------------------------------------------------------------------
// Generic tiled fp32 GEMM (pre-pass only)
// ---------------------------------------------------------------------------
__global__ __launch_bounds__(256) void gemm_f32(
    const float* __restrict__ A, const float* __restrict__ B,
    const float* __restrict__ bias, float* __restrict__ C,
    int M, int N, int K, int lda, int ldb, int ldc)
{
  __shared__ float As[16][132];
  __shared__ float Bs[16][64];
  const int bm = blockIdx.x * 128, bn = blockIdx.y * 64;
  const int tid = threadIdx.x;
  const int tx = tid & 15, ty = tid >> 4;
  float acc[8][4];
  #pragma unroll
  for (int i = 0; i < 8; ++i)
    #pragma unroll
    for (int j = 0; j < 4; ++j) acc[i][j] = 0.f;

  for (int kt = 0; kt < K; kt += 16) {
    #pragma unroll
    for (int i = 0; i < 2; ++i) {
      int li = tid + i*256;
      int r = li >> 2, q = li & 3;
      float4 a4 = *(const float4*)(A + (size_t)(bm + r)*lda + kt + q*4);
      As[q*4+0][r] = a4.x; As[q*4+1][r] = a4.y;
      As[q*4+2][r] = a4.z; As[q*4+3][r] = a4.w;
    }
    {
      int k = tid >> 4, nq = tid & 15;
      *(float4*)(&Bs[k][nq*4]) = *(const float4*)(B + (size_t)(kt + k)*ldb + bn + nq*4);
    }
    __syncthreads();
    #pragma unroll
    for (int kk = 0; kk < 16; ++kk) {
      float av[8], bv[4];
      *(float4*)(av)   = *(const float4*)(&As[kk][ty*8]);
      *(float4*)(av+4) = *(const float4*)(&As[kk][ty*8+4]);
      *(float4*)(bv)   = *(const float4*)(&Bs[kk][tx*4]);
      #pragma unroll
      for (int i = 0; i < 8; ++i)
        #pragma unroll
        for (int j = 0; j < 4; ++j) acc[i][j] += av[i]*bv[j];
    }
    __syncthreads();
  }
  #pragma unroll
  for (int i = 0; i < 8; ++i) {
    int m = bm + ty*8 + i;
    #pragma unroll
    for (int j = 0; j < 4; ++j) {
      int n = bn + tx*4 + j;
      float v = acc[i][j];
      if (bias) v += bias[n];
      C[(size_t)m*ldc + n] = v;
    }
  }
}

// ---------------------------------------------------------------------------
// Setup: Wcat (row-major [576][4608]) static parts + c0.
// ---------------------------------------------------------------------------
__global__ __launch_bounds__(512) void setup_kernel(
    const float* __restrict__ W_hm, const float* __restrict__ fc2_w,
    const float* __restrict__ W_um, const float* __restrict__ W_hh,
    const float* __restrict__ bias, const float* __restrict__ fc2_b,
    float* __restrict__ Wcat, float* __restrict__ c0)
{
  const int idx = blockIdx.x * 512 + threadIdx.x;
  if (idx < 512*1536) {                       // rows 0:512, cols 0:1536
    int k = idx / 1536, c = idx % 1536;
    float v;
    if (c < 512)       v = W_hm[k*512 + c];
    else if (c < 1024) v = fc2_w[k*512 + (c-512)];
    else               v = fc2_w[(size_t)(512+k)*512 + (c-1024)];
    Wcat[(size_t)k*4608 + c] = v;
    return;
  }
  int i = idx - 512*1536;
  if (i < 64*4608) {                          // rows 512:576, all cols
    int k2 = i / 4608, c = i % 4608;
    Wcat[(size_t)(512+k2)*4608 + c] = (c < 512) ? W_um[k2*512 + c] : 0.f;
    return;
  }
  i -= 64*4608;
  if (i < 1536) {                             // c0 = fc2_b@W_hh + bias_hh
    float s = bias[1536 + i];
    for (int m = 0; m < 512; ++m) s += fc2_b[m] * W_hh[(size_t)m*1536 + i];
    c0[i] = s;
  }
}

// ---------------------------------------------------------------------------
// Persistent scan. Blocks 0..31: BC (batch). Blocks 32..223: GEMM (24 cols).
// GEMM: per-wave K-region of 72 rows (2 segments of 36), thread tile 2b x 12c,
// shuffle + LDS reduce. 8 GEMM-arrival lines / 4 BC-arrival lines.
// ---------------------------------------------------------------------------
__global__ __launch_bounds__(NTHR, 1) void persist_kernel(
    const float* __restrict__ P1, const float* __restrict__ P2,
    const float* __restrict__ Wcat, float* __restrict__ oc,
    float* __restrict__ hTx_all, float* __restrict__ hnew_part,
    float* __restrict__ whh_part, const float* __restrict__ c0,
    const float* __restrict__ fc1_w, const float* __restrict__ fc1_b,
    const float* __restrict__ fc2_b, const float* __restrict__ u_noise,
    const int* __restrict__ length, const float* __restrict__ fc_w,
    const float* __restrict__ fc_b, float* __restrict__ out,
    int* __restrict__ bar)
{
  __shared__ float smem[25600];    // GEMM: hxs[18432] + red[7168]; BC: scratch
  const int bid = blockIdx.x;
  const int tid = threadIdx.x;

  if (bid >= 32) {
    // ================= GEMM block: 24 cols =================
    const int gb   = bid - 32;
    const int c0g  = gb * 24;
    const int lineA= gb & 7;
    const int s    = tid >> 5;           // K-segment 0..15 (36 k each)
    const int tile = tid & 31;
    const int co   = tile & 1;           // col-half: 12 cols
    const int bq   = tile >> 1;          // 0..15 (2 batches)
    const int wv   = tid >> 6;           // wave 0..7
    const int kbase= s * 36;
    const int lane = tid & 63;
    float* hxs = smem;                   // [576][32]
    float* red = smem + 18432;           // [8][32][28]

    for (int t = 0; t < 128; ++t) {
      // wait until h(t) published (4 lines, parallel pollers)
      if (tid < 4) {
        while (cohLoadI(&bar[256 + tid*32]) < t*8) __builtin_amdgcn_s_sleep(1);
      }
      __syncthreads();
      // per-wave stage of the wave's 72-row region [wv*72, wv*72+72) x 32
      // (2304 floats, 18 float2/lane). Covers BOTH of this wave's K-segments;
      // intra-wave ds_write -> ds_read is in-order, no block barrier needed.
      {
        const float* hsrc = hTx_all + (size_t)t*HTXS + wv*72*32;
        float* hdst = hxs + wv*72*32;
        #pragma unroll
        for (int j = 0; j < 18; ++j)
          *(float2*)(hdst + lane*2 + j*128) =
              *(const float2*)(hsrc + lane*2 + j*128);
      }
      // register-tiled outer product (reads only own wave's staged region)
      float acc[2][12];
      #pragma unroll
      for (int bi = 0; bi < 2; ++bi)
        #pragma unroll
        for (int cj = 0; cj < 12; ++cj) acc[bi][cj] = 0.f;
      const float* wp = Wcat + (size_t)kbase*4608 + c0g + co*12;
      const float* hp = hxs + kbase*32 + bq*2;
      #pragma unroll 4
      for (int kk = 0; kk < 36; ++kk) {
        float2 h2 = *(const float2*)(hp); hp += 32;
        float4 wa = *(const float4*)(wp);
        float4 wb = *(const float4*)(wp + 4);
        float4 wc = *(const float4*)(wp + 8); wp += 4608;
        float wvv[12] = {wa.x, wa.y, wa.z, wa.w, wb.x, wb.y, wb.z, wb.w,
                         wc.x, wc.y, wc.z, wc.w};
        #pragma unroll
        for (int cj = 0; cj < 12; ++cj) {
          acc[0][cj] += h2.x * wvv[cj];
          acc[1][cj] += h2.y * wvv[cj];
        }
      }
      // combine the wave's two K-segments (lane ^ 32)
      #pragma unroll
      for (int bi = 0; bi < 2; ++bi)
        #pragma unroll
        for (int cj = 0; cj < 12; ++cj)
          acc[bi][cj] += __shfl_xor(acc[bi][cj], 32);
      if ((tid & 32) == 0) {             // low half writes wave partial
        float* rp = red + wv*896 + (bq*2)*28 + co*12;
        #pragma unroll
        for (int bi = 0; bi < 2; ++bi) {
          *(float4*)(rp + bi*28)     = make_float4(acc[bi][0], acc[bi][1], acc[bi][2], acc[bi][3]);
          *(float4*)(rp + bi*28 + 4) = make_float4(acc[bi][4], acc[bi][5], acc[bi][6], acc[bi][7]);
          *(float4*)(rp + bi*28 + 8) = make_float4(acc[bi][8], acc[bi][9], acc[bi][10], acc[bi][11]);
        }
      }
      __syncthreads();
      // final 8-wave reduce + sc1 store to oc
      if (tid < 384) {
        int v = tid*2;
        int b = v / 24, c = v - b*24;
        const float* rp = red + b*28 + c;
        float s0 = 0.f, s1 = 0.f;
        #pragma unroll
        for (int w = 0; w < 8; ++w) { s0 += rp[w*896]; s1 += rp[w*896 + 1]; }
        float* op = oc + (size_t)b*4608 + c0g + c;
        cohStore(op, s0); cohStore(op + 1, s1);
      }
      __syncthreads();                   // drain sc1 stores (vmcnt 0)
      if (tid == 0)
        __hip_atomic_fetch_add(&bar[lineA*32], 1, __ATOMIC_RELAXED, __HIP_MEMORY_SCOPE_AGENT);
    }
  } else {
    // ================= BC block: batch b =================
    const int b = bid;
    const int lenb = length[b];
    float hcur = 0.f;
    float usage_r = -99999.f;            // valid for tid<64
    int jprev = 0;                       // thread-0 only
    int* flg = (int*)(smem + 1100);
    // hoisted constants
    const float c0r = c0[tid], c0z = c0[512 + tid], c0n = c0[1024 + tid];
    const float fc2bv = fc2_b[tid];
    const float f1b = (tid < 64) ? fc1_b[tid] : 0.f;
    const int n_ = tid & 63, kg_ = tid >> 6;
    const float* fw = fc1_w + (size_t)kg_*64*64 + n_;

    for (int t = 0; t < 128; ++t) {
      const int t32b = t*32 + b;
      // prefetch step inputs (independent of barrier)
      const float* p1p = P1 + (size_t)t32b*1536;
      float p1r = p1p[tid], p1z = p1p[512 + tid], p1n = p1p[1024 + tid];
      float p2v = P2[(size_t)t32b*512 + tid];
      float uval = (tid < 64) ? u_noise[(size_t)t32b*64 + tid] : 0.f;
      // wait for all 192 GEMM blocks (8 lines, parallel pollers)
      if (tid < 8) {
        const int tgt = (t + 1) * 24;
        while (cohLoadI(&bar[tid*32]) < tgt) __builtin_amdgcn_s_sleep(1);
      }
      __syncthreads();
      const float* ocb = oc + (size_t)b*4608;
      float oct  = cohLoad(ocb + tid);
      float vA   = cohLoad(ocb + 512  + tid);
      float vB   = cohLoad(ocb + 1024 + tid);
      float vAW0 = cohLoad(ocb + 1536 + tid);
      float vAW1 = cohLoad(ocb + 2048 + tid);
      float vAW2 = cohLoad(ocb + 2560 + tid);
      float vBW0 = cohLoad(ocb + 3072 + tid);
      float vBW1 = cohLoad(ocb + 3584 + tid);
      float vBW2 = cohLoad(ocb + 4096 + tid);
      smem[tid] = tanhf(p2v + oct);      // th
      __syncthreads();
      {                                  // fc1 partial dots
        float sdot = 0.f;
        #pragma unroll 8
        for (int k = 0; k < 64; ++k) sdot += smem[kg_*64 + k] * fw[(size_t)k*64];
        smem[512 + tid] = sdot;
      }
      __syncthreads();
      if (tid < 64) {                    // logits + Gumbel + wave argmax
        float l = f1b;
        #pragma unroll
        for (int kg = 0; kg < 8; ++kg) l += smem[512 + kg*64 + tid];
        l += -logf(1e-20f - logf(1e-20f + uval));
        float best = l; int idx = tid;
        #pragma unroll
        for (int off = 32; off >= 1; off >>= 1) {
          float ob = __shfl_xor(best, off);
          int   oi = __shfl_xor(idx,  off);
          if (ob > best || (ob == best && oi < idx)) { best = ob; idx = oi; }
        }
        if (tid == 0) {
          flg[0] = idx;
          flg[1] = (t < 64) ? t : jprev;
          jprev = idx;
        }
      }
      __syncthreads();
      const int jj = flg[0], ss = flg[1];
      // gates
      float hnp, w0, w1, w2;
      if (jj == ss) { hnp = vA; w0 = vAW0; w1 = vAW1; w2 = vAW2; }
      else {
        hnp = hnew_part[(size_t)(b*64 + jj)*512 + tid];
        const float* wpp = whh_part + (size_t)(b*64 + jj)*1536;
        w0 = wpp[tid]; w1 = wpp[512 + tid]; w2 = wpp[1024 + tid];
      }
      float h_new = hnp + vB + fc2bv;
      float wh_r = w0 + vBW0 + c0r;
      float wh_z = w1 + vBW1 + c0z;
      float wh_n = w2 + vBW2 + c0n;
      float r  = 1.f / (1.f + expf(-(p1r + wh_r)));
      float z  = 1.f / (1.f + expf(-(p1z + wh_z)));
      float nn = tanhf(p1n + r*wh_n);
      float h1 = (1.f - z)*nn + z*h_new;
      if (t >= lenb) h1 = hcur;
      hcur = h1;
      // publish h(t+1) + lu via sc1 (k-major [576][32])
      float* hw = hTx_all + (size_t)(t + 1)*HTXS;
      cohStore(&hw[tid*32 + b], h1);
      if (tid < 64) {
        float un = (usage_r - 1.f) * (tid == jj ? 0.f : 1.f);
        usage_r = un;
        cohStore(&hw[(512 + tid)*32 + b], 1.f / (1.f + expf(-un)));
      }
      smem[tid] = h1;                    // published by arrive's syncthreads
      __syncthreads();                   // drain sc1 stores
      if (tid == 0)
        __hip_atomic_fetch_add(&bar[256 + (b & 3)*32], 1, __ATOMIC_RELAXED, __HIP_MEMORY_SCOPE_AGENT);
      // ---- off critical path: slot caches + output projection ----
      hnew_part[(size_t)(b*64 + ss)*512 + tid] = vA;
      float* wps = whh_part + (size_t)(b*64 + ss)*1536;
      wps[tid] = vAW0; wps[512 + tid] = vAW1; wps[1024 + tid] = vAW2;
      {
        int a = tid & 31, jg = tid >> 5;
        float sp = 0.f;
        #pragma unroll 8
        for (int jx = 0; jx < 32; ++jx)
          sp += smem[jg*32 + jx] * fc_w[(size_t)(jg*32 + jx)*32 + a];
        smem[512 + tid] = sp;
      }
      __syncthreads();
      if (tid < 32) {
        float s2 = fc_b[tid];
        #pragma unroll
        for (int jg = 0; jg < 16; ++jg) s2 += smem[512 + jg*32 + tid];
        out[(size_t)t32b*32 + tid] = s2;
      }
    }
  }
}

// ---------------------------------------------------------------------------
extern "C" void kernel_launch(void* const* d_in, const int* in_sizes, int n_in,
                              void* d_out, int out_size, void* d_ws, size_t ws_size,
                              hipStream_t stream)
{
  const float* x      = (const float*)d_in[0];
  const int*   length = (const int*)  d_in[1];
  const float* u_nois = (const float*)d_in[2];
  const float* W_ih   = (const float*)d_in[3];
  const float* W_hh   = (const float*)d_in[4];
  const float* bias   = (const float*)d_in[5];
  const float* W_im   = (const float*)d_in[6];
  const float* W_hm   = (const float*)d_in[7];
  const float* W_um   = (const float*)d_in[8];
  const float* fc1_w  = (const float*)d_in[9];
  const float* fc1_b  = (const float*)d_in[10];
  const float* fc2_w  = (const float*)d_in[11];
  const float* fc2_b  = (const float*)d_in[12];
  const float* fc_w   = (const float*)d_in[13];
  const float* fc_b   = (const float*)d_in[14];
  float* out = (float*)d_out;

  float* ws   = (float*)d_ws;
  int*   bar  = (int*)d_ws;
  float* hTx  = ws + OFF_HTX;
  float* oc   = ws + OFF_OC;
  float* hnew = ws + OFF_HNEW;
  float* whh  = ws + OFF_WHH;
  float* c0   = ws + OFF_C0;
  float* Wcat = ws + OFF_WCAT;
  float* P1   = ws + OFF_P1;
  float* P2   = ws + OFF_P2;

  // zero: barrier lines + hTx buffer 0 (h=0, lu=0); slot caches (mem=0)
  hipMemsetAsync(d_ws, 0, (size_t)(OFF_HTX + HTXS) * sizeof(float), stream);
  hipMemsetAsync(hnew, 0, (size_t)(32*64*512 + 32*64*1536) * sizeof(float), stream);

  setup_kernel<<<2115, 512, 0, stream>>>(W_hm, fc2_w, W_um, W_hh, bias, fc2_b,
                                         Wcat, c0);

  // M_A = fc2_A@W_hh -> Wcat cols 1536:3072 ; M_B = fc2_B@W_hh -> 3072:4608
  { dim3 g(4, 24);
    gemm_f32<<<g, 256, 0, stream>>>(fc2_w,                   W_hh, nullptr, Wcat + 1536,
                                    512, 1536, 512, 512, 1536, 4608);
    gemm_f32<<<g, 256, 0, stream>>>(fc2_w + (size_t)512*512, W_hh, nullptr, Wcat + 3072,
                                    512, 1536, 512, 512, 1536, 4608); }
  // P1 = x@W_ih + bias_ih ; P2 = x@W_im
  { dim3 g(32, 24);
    gemm_f32<<<g, 256, 0, stream>>>(x, W_ih, bias, P1, 4096, 1536, 512, 512, 1536, 1536); }
  { dim3 g(32, 8);
    gemm_f32<<<g, 256, 0, stream>>>(x, W_im, nullptr, P2, 4096, 512, 512, 512, 512, 512); }

  persist_kernel<<<NBLK, NTHR, 0, stream>>>(P1, P2, Wcat, oc, hTx, hnew, whh,
                                            c0, fc1_w, fc1_b, fc2_b, u_nois,
                                            length, fc_w, fc_b, out, bar);
}

// Round 7
// 2395.299 us; speedup vs baseline: 4.2312x; 1.0357x over previous
//
#include <hip/hip_runtime.h>
#include <hip/hip_bf16.h>
#include <math.h>

// T=128, B=32, D=512, H=512, N=64, A=32, TAU=1
#define NTHR  512
#define NBLK  224              // 32 BC blocks + 192 GEMM blocks
#define HTXS  19456            // hTx buffer stride (2*9216 + pad)

// ---- flag area (int offsets into d_ws) ----
// hflag[b]  = bar[b*32]            (32 lines; BC plain-stores t+1)
// wflag[g]  = bar[1024 + g*32]     (192 lines; GEMM g plain-stores t+1)
//   g = cg*2+bg ; cg<32 -> cols [0,1536) = "early" blocks
#define OFF_HTX  8192                       // hTx_all: [129][2][576][16]
#define OFF_OC   (OFF_HTX + 129*HTXS)       // oc: [32][4608]
#define OFF_HNEW (OFF_OC + 32*4608)         // hnew_part: [32][64][512]
#define OFF_WHH  (OFF_HNEW + 32*64*512)     // whh_part: [32][64][1536]
#define OFF_C0   (OFF_WHH + 32*64*1536)     // c0: [1536]
#define OFF_WCAT (OFF_C0 + 1536)            // Wcat: [576][4608] row-major
#define OFF_P1   (OFF_WCAT + 576*4608)      // P1: [4096][1536]
#define OFF_P2   (OFF_P1 + 4096*1536)       // P2: [4096][512]
// end = OFF_P2 + 4096*512 ≈ 71.6 MB

// sc1 (agent-scope) ops: bypass per-XCD L2, coherent at LLC.
__device__ __forceinline__ float cohLoad(const float* p) {
  return __hip_atomic_load(p, __ATOMIC_RELAXED, __HIP_MEMORY_SCOPE_AGENT);
}
__device__ __forceinline__ void cohStore(float* p, float v) {
  __hip_atomic_store(p, v, __ATOMIC_RELAXED, __HIP_MEMORY_SCOPE_AGENT);
}
__device__ __forceinline__ int cohLoadI(const int* p) {
  return __hip_atomic_load(p, __ATOMIC_RELAXED, __HIP_MEMORY_SCOPE_AGENT);
}
__device__ __forceinline__ void cohStoreI(int* p, int v) {
  __hip_atomic_store(p, v, __ATOMIC_RELAXED, __HIP_MEMORY_SCOPE_AGENT);
}

// ---------------------------------------------------------------------------
// Generic tiled fp32 GEMM (pre-pass only)
// ---------------------------------------------------------------------------
__global__ __launch_bounds__(256) void gemm_f32(
    const float* __restrict__ A, const float* __restrict__ B,
    const float* __restrict__ bias, float* __restrict__ C,
    int M, int N, int K, int lda, int ldb, int ldc)
{
  __shared__ float As[16][132];
  __shared__ float Bs[16][64];
  const int bm = blockIdx.x * 128, bn = blockIdx.y * 64;
  const int tid = threadIdx.x;
  const int tx = tid & 15, ty = tid >> 4;
  float acc[8][4];
  #pragma unroll
  for (int i = 0; i < 8; ++i)
    #pragma unroll
    for (int j = 0; j < 4; ++j) acc[i][j] = 0.f;

  for (int kt = 0; kt < K; kt += 16) {
    #pragma unroll
    for (int i = 0; i < 2; ++i) {
      int li = tid + i*256;
      int r = li >> 2, q = li & 3;
      float4 a4 = *(const float4*)(A + (size_t)(bm + r)*lda + kt + q*4);
      As[q*4+0][r] = a4.x; As[q*4+1][r] = a4.y;
      As[q*4+2][r] = a4.z; As[q*4+3][r] = a4.w;
    }
    {
      int k = tid >> 4, nq = tid & 15;
      *(float4*)(&Bs[k][nq*4]) = *(const float4*)(B + (size_t)(kt + k)*ldb + bn + nq*4);
    }
    __syncthreads();
    #pragma unroll
    for (int kk = 0; kk < 16; ++kk) {
      float av[8], bv[4];
      *(float4*)(av)   = *(const float4*)(&As[kk][ty*8]);
      *(float4*)(av+4) = *(const float4*)(&As[kk][ty*8+4]);
      *(float4*)(bv)   = *(const float4*)(&Bs[kk][tx*4]);
      #pragma unroll
      for (int i = 0; i < 8; ++i)
        #pragma unroll
        for (int j = 0; j < 4; ++j) acc[i][j] += av[i]*bv[j];
    }
    __syncthreads();
  }
  #pragma unroll
  for (int i = 0; i < 8; ++i) {
    int m = bm + ty*8 + i;
    #pragma unroll
    for (int j = 0; j < 4; ++j) {
      int n = bn + tx*4 + j;
      float v = acc[i][j];
      if (bias) v += bias[n];
      C[(size_t)m*ldc + n] = v;
    }
  }
}

// ---------------------------------------------------------------------------
// Setup: Wcat (row-major [576][4608]) static parts + c0.
// ---------------------------------------------------------------------------
__global__ __launch_bounds__(512) void setup_kernel(
    const float* __restrict__ W_hm, const float* __restrict__ fc2_w,
    const float* __restrict__ W_um, const float* __restrict__ W_hh,
    const float* __restrict__ bias, const float* __restrict__ fc2_b,
    float* __restrict__ Wcat, float* __restrict__ c0)
{
  const int idx = blockIdx.x * 512 + threadIdx.x;
  if (idx < 512*1536) {                       // rows 0:512, cols 0:1536
    int k = idx / 1536, c = idx % 1536;
    float v;
    if (c < 512)       v = W_hm[k*512 + c];
    else if (c < 1024) v = fc2_w[k*512 + (c-512)];
    else               v = fc2_w[(size_t)(512+k)*512 + (c-1024)];
    Wcat[(size_t)k*4608 + c] = v;
    return;
  }
  int i = idx - 512*1536;
  if (i < 64*4608) {                          // rows 512:576, all cols
    int k2 = i / 4608, c = i % 4608;
    Wcat[(size_t)(512+k2)*4608 + c] = (c < 512) ? W_um[k2*512 + c] : 0.f;
    return;
  }
  i -= 64*4608;
  if (i < 1536) {                             // c0 = fc2_b@W_hh + bias_hh
    float s = bias[1536 + i];
    for (int m = 0; m < 512; ++m) s += fc2_b[m] * W_hh[(size_t)m*1536 + i];
    c0[i] = s;
  }
}

// ---------------------------------------------------------------------------
// Persistent scan. Blocks 0..31: BC (batch). Blocks 32..223: GEMM.
// GEMM block g=cg*2+bg: cols [cg*48, cg*48+48), batches [bg*16, bg*16+16).
// Thread tile: (kseg8 x col16 x bq4): 3 cols x 4 batches, K-seg of 72.
// All cross-block signals are plain sc1 stores to per-block flag words.
// ---------------------------------------------------------------------------
__global__ __launch_bounds__(NTHR, 1) void persist_kernel(
    const float* __restrict__ P1, const float* __restrict__ P2,
    const float* __restrict__ Wcat, float* __restrict__ oc,
    float* __restrict__ hTx_all, float* __restrict__ hnew_part,
    float* __restrict__ whh_part, const float* __restrict__ c0,
    const float* __restrict__ fc1_w, const float* __restrict__ fc1_b,
    const float* __restrict__ fc2_b, const float* __restrict__ u_noise,
    const int* __restrict__ length, const float* __restrict__ fc_w,
    const float* __restrict__ fc_b, float* __restrict__ out,
    int* __restrict__ bar)
{
  __shared__ float smem[15424];    // GEMM: hxs[9216] + red[8*776]; BC: scratch
  const int bid = blockIdx.x;
  const int tid = threadIdx.x;

  if (bid >= 32) {
    // ================= GEMM block =================
    const int gb  = bid - 32;            // 0..191
    const int cg  = gb >> 1;             // 0..95
    const int bg  = gb & 1;              // batch half
    const int colbase = cg * 48;
    const int s   = tid >> 6;            // K-seg 0..7 (72 rows)
    const int c   = (tid >> 2) & 15;     // col-triple 0..15
    const int bq  = tid & 3;             // batch-quad 0..3
    const int kbase = s * 72;
    float* hxs = smem;                   // [576][16] (this batch-half)
    float* red = smem + 9216;            // [8][776] (768 used + pad)

    for (int t = 0; t < 128; ++t) {
      // wait for my 16 batches' h(t)
      if (tid < 16) {
        while (cohLoadI(&bar[(bg*16 + tid)*32]) < t) __builtin_amdgcn_s_sleep(1);
      }
      __syncthreads();
      // stage hx half: 9216 floats = 36 KB (dense, fresh lines)
      const float* hsrc = hTx_all + (size_t)t*HTXS + bg*9216;
      for (int i = tid; i < 2304; i += NTHR)
        *(float4*)(hxs + i*4) = *(const float4*)(hsrc + i*4);
      __syncthreads();
      // 3 cols x 4 batches register tile over K-seg of 72
      float acc[4][3];
      #pragma unroll
      for (int bi = 0; bi < 4; ++bi)
        #pragma unroll
        for (int cj = 0; cj < 3; ++cj) acc[bi][cj] = 0.f;
      const float* wp = Wcat + (size_t)kbase*4608 + colbase + c*3;
      const float* hp = hxs + kbase*16 + bq*4;
      #pragma unroll 4
      for (int kk = 0; kk < 72; ++kk) {
        float4 h4 = *(const float4*)(hp); hp += 16;
        float w0 = wp[0], w1 = wp[1], w2 = wp[2]; wp += 4608;
        acc[0][0] += h4.x*w0; acc[0][1] += h4.x*w1; acc[0][2] += h4.x*w2;
        acc[1][0] += h4.y*w0; acc[1][1] += h4.y*w1; acc[1][2] += h4.y*w2;
        acc[2][0] += h4.z*w0; acc[2][1] += h4.z*w1; acc[2][2] += h4.z*w2;
        acc[3][0] += h4.w*w0; acc[3][1] += h4.w*w1; acc[3][2] += h4.w*w2;
      }
      // write K-seg partials
      {
        float* rp = red + s*776 + (bq*4)*48 + c*3;
        #pragma unroll
        for (int bi = 0; bi < 4; ++bi) {
          rp[bi*48 + 0] = acc[bi][0];
          rp[bi*48 + 1] = acc[bi][1];
          rp[bi*48 + 2] = acc[bi][2];
        }
      }
      __syncthreads();
      // 8-seg reduce + sc1 store to oc
      for (int i = tid; i < 768; i += NTHR) {
        float ssum = 0.f;
        #pragma unroll
        for (int w = 0; w < 8; ++w) ssum += red[w*776 + i];
        int b16 = i / 48, cc = i - b16*48;
        cohStore(&oc[(size_t)(bg*16 + b16)*4608 + colbase + cc], ssum);
      }
      __syncthreads();                   // drain sc1 stores (vmcnt 0)
      if (tid == 0) cohStoreI(&bar[1024 + gb*32], t + 1);
    }
  } else {
    // ================= BC block: batch b =================
    const int b = bid;
    const int lenb = length[b];
    float hcur = 0.f;
    float usage_r = -99999.f;            // valid for tid<64
    int jprev = 0;                       // thread-0 only
    int* flg = (int*)(smem + 1100);
    const float c0r = c0[tid], c0z = c0[512 + tid], c0n = c0[1024 + tid];
    const float fc2bv = fc2_b[tid];
    const float f1b = (tid < 64) ? fc1_b[tid] : 0.f;
    const int n_ = tid & 63, kg_ = tid >> 6;
    const float* fw = fc1_w + (size_t)kg_*64*64 + n_;

    for (int t = 0; t < 128; ++t) {
      const int t32b = t*32 + b;
      // prefetch step inputs (independent of flags)
      const float* p1p = P1 + (size_t)t32b*1536;
      float p1r = p1p[tid], p1z = p1p[512 + tid], p1n = p1p[1024 + tid];
      float p2v = P2[(size_t)t32b*512 + tid];
      float uval = (tid < 64) ? u_noise[(size_t)t32b*64 + tid] : 0.f;
      // ---- wait EARLY blocks (cols 0:1536): wflag[0..63] ----
      if (tid < 64) {
        while (cohLoadI(&bar[1024 + tid*32]) < t + 1) __builtin_amdgcn_s_sleep(1);
      }
      __syncthreads();
      const float* ocb = oc + (size_t)b*4608;
      float oct = cohLoad(ocb + tid);
      float vA  = cohLoad(ocb + 512  + tid);
      float vB  = cohLoad(ocb + 1024 + tid);
      smem[tid] = tanhf(p2v + oct);      // th
      __syncthreads();
      {                                  // fc1 partial dots
        float sdot = 0.f;
        #pragma unroll 8
        for (int k = 0; k < 64; ++k) sdot += smem[kg_*64 + k] * fw[(size_t)k*64];
        smem[512 + tid] = sdot;
      }
      __syncthreads();
      if (tid < 64) {                    // logits + Gumbel + wave argmax
        float l = f1b;
        #pragma unroll
        for (int kg = 0; kg < 8; ++kg) l += smem[512 + kg*64 + tid];
        l += -logf(1e-20f - logf(1e-20f + uval));
        float best = l; int idx = tid;
        #pragma unroll
        for (int off = 32; off >= 1; off >>= 1) {
          float ob = __shfl_xor(best, off);
          int   oi = __shfl_xor(idx,  off);
          if (ob > best || (ob == best && oi < idx)) { best = ob; idx = oi; }
        }
        if (tid == 0) {
          flg[0] = idx;
          flg[1] = (t < 64) ? t : jprev;
          jprev = idx;
        }
      }
      // ---- wait LATE blocks (cols 1536:4608): wflag[64..191] ----
      if (tid < 128) {
        while (cohLoadI(&bar[1024 + (64 + tid)*32]) < t + 1) __builtin_amdgcn_s_sleep(1);
      }
      __syncthreads();
      const int jj = flg[0], ss = flg[1];
      float vAW0 = cohLoad(ocb + 1536 + tid);
      float vAW1 = cohLoad(ocb + 2048 + tid);
      float vAW2 = cohLoad(ocb + 2560 + tid);
      float vBW0 = cohLoad(ocb + 3072 + tid);
      float vBW1 = cohLoad(ocb + 3584 + tid);
      float vBW2 = cohLoad(ocb + 4096 + tid);
      float hnp, w0, w1, w2;
      if (jj == ss) { hnp = vA; w0 = vAW0; w1 = vAW1; w2 = vAW2; }
      else {
        hnp = hnew_part[(size_t)(b*64 + jj)*512 + tid];
        const float* wpp = whh_part + (size_t)(b*64 + jj)*1536;
        w0 = wpp[tid]; w1 = wpp[512 + tid]; w2 = wpp[1024 + tid];
      }
      float h_new = hnp + vB + fc2bv;
      float wh_r = w0 + vBW0 + c0r;
      float wh_z = w1 + vBW1 + c0z;
      float wh_n = w2 + vBW2 + c0n;
      float r  = 1.f / (1.f + expf(-(p1r + wh_r)));
      float z  = 1.f / (1.f + expf(-(p1z + wh_z)));
      float nn = tanhf(p1n + r*wh_n);
      float h1 = (1.f - z)*nn + z*h_new;
      if (t >= lenb) h1 = hcur;
      hcur = h1;
      // publish h(t+1)+lu into half (b>>4), layout [576][16]
      float* hw = hTx_all + (size_t)(t + 1)*HTXS + (b >> 4)*9216;
      cohStore(&hw[tid*16 + (b & 15)], h1);
      if (tid < 64) {
        float un = (usage_r - 1.f) * (tid == jj ? 0.f : 1.f);
        usage_r = un;
        cohStore(&hw[(512 + tid)*16 + (b & 15)], 1.f / (1.f + expf(-un)));
      }
      smem[tid] = h1;                    // for out projection below
      __syncthreads();                   // drain sc1 stores
      if (tid == 0) cohStoreI(&bar[b*32], t + 1);
      // ---- off critical path: slot caches + output projection ----
      hnew_part[(size_t)(b*64 + ss)*512 + tid] = vA;
      float* wps = whh_part + (size_t)(b*64 + ss)*1536;
      wps[tid] = vAW0; wps[512 + tid] = vAW1; wps[1024 + tid] = vAW2;
      {
        int a = tid & 31, jg = tid >> 5;
        float sp = 0.f;
        #pragma unroll 8
        for (int jx = 0; jx < 32; ++jx)
          sp += smem[jg*32 + jx] * fc_w[(size_t)(jg*32 + jx)*32 + a];
        smem[512 + tid] = sp;
      }
      __syncthreads();
      if (tid < 32) {
        float s2 = fc_b[tid];
        #pragma unroll
        for (int jg = 0; jg < 16; ++jg) s2 += smem[512 + jg*32 + tid];
        out[(size_t)t32b*32 + tid] = s2;
      }
    }
  }
}

// ---------------------------------------------------------------------------
extern "C" void kernel_launch(void* const* d_in, const int* in_sizes, int n_in,
                              void* d_out, int out_size, void* d_ws, size_t ws_size,
                              hipStream_t stream)
{
  const float* x      = (const float*)d_in[0];
  const int*   length = (const int*)  d_in[1];
  const float* u_nois = (const float*)d_in[2];
  const float* W_ih   = (const float*)d_in[3];
  const float* W_hh   = (const float*)d_in[4];
  const float* bias   = (const float*)d_in[5];
  const float* W_im   = (const float*)d_in[6];
  const float* W_hm   = (const float*)d_in[7];
  const float* W_um   = (const float*)d_in[8];
  const float* fc1_w  = (const float*)d_in[9];
  const float* fc1_b  = (const float*)d_in[10];
  const float* fc2_w  = (const float*)d_in[11];
  const float* fc2_b  = (const float*)d_in[12];
  const float* fc_w   = (const float*)d_in[13];
  const float* fc_b   = (const float*)d_in[14];
  float* out = (float*)d_out;

  float* ws   = (float*)d_ws;
  int*   bar  = (int*)d_ws;
  float* hTx  = ws + OFF_HTX;
  float* oc   = ws + OFF_OC;
  float* hnew = ws + OFF_HNEW;
  float* whh  = ws + OFF_WHH;
  float* c0   = ws + OFF_C0;
  float* Wcat = ws + OFF_WCAT;
  float* P1   = ws + OFF_P1;
  float* P2   = ws + OFF_P2;

  // zero: flag words + hTx buffer 0 (h=0, lu=0); slot caches (mem=0)
  hipMemsetAsync(d_ws, 0, (size_t)(OFF_HTX + HTXS) * sizeof(float), stream);
  hipMemsetAsync(hnew, 0, (size_t)(32*64*512 + 32*64*1536) * sizeof(float), stream);

  setup_kernel<<<2115, 512, 0, stream>>>(W_hm, fc2_w, W_um, W_hh, bias, fc2_b,
                                         Wcat, c0);

  // M_A = fc2_A@W_hh -> Wcat cols 1536:3072 ; M_B = fc2_B@W_hh -> 3072:4608
  { dim3 g(4, 24);
    gemm_f32<<<g, 256, 0, stream>>>(fc2_w,                   W_hh, nullptr, Wcat + 1536,
                                    512, 1536, 512, 512, 1536, 4608);
    gemm_f32<<<g, 256, 0, stream>>>(fc2_w + (size_t)512*512, W_hh, nullptr, Wcat + 3072,
                                    512, 1536, 512, 512, 1536, 4608); }
  // P1 = x@W_ih + bias_ih ; P2 = x@W_im
  { dim3 g(32, 24);
    gemm_f32<<<g, 256, 0, stream>>>(x, W_ih, bias, P1, 4096, 1536, 512, 512, 1536, 1536); }
  { dim3 g(32, 8);
    gemm_f32<<<g, 256, 0, stream>>>(x, W_im, nullptr, P2, 4096, 512, 512, 512, 512, 512); }

  persist_kernel<<<NBLK, NTHR, 0, stream>>>(P1, P2, Wcat, oc, hTx, hnew, whh,
                                            c0, fc1_w, fc1_b, fc2_b, u_nois,
                                            length, fc_w, fc_b, out, bar);
}

// Round 8
// 2387.877 us; speedup vs baseline: 4.2444x; 1.0031x over previous
//
#include <hip/hip_runtime.h>
#include <hip/hip_bf16.h>
#include <math.h>

// T=128, B=32, D=512, H=512, N=64, A=32, TAU=1
#define NTHR  512
#define NBLK  224              // 32 BC blocks + 192 GEMM blocks
#define HTXS  19456            // hTx buffer stride (2*9216 + pad)

// ---- flag area (int offsets into d_ws) ----
// hflag[b]  = bar[b*32]            (32 lines; BC plain sc1-stores t+1)
// wflag[g]  = bar[1024 + g*32]     (192 lines; GEMM g plain sc1-stores t+1)
//   g = cg*2+bg ; cg<32 -> cols [0,1536) = "early" blocks
#define OFF_HTX  8192                       // hTx_all: [129][2][576][16]
#define OFF_OC   (OFF_HTX + 129*HTXS)       // oc: [32][4608]
#define OFF_HNEW (OFF_OC + 32*4608)         // hnew_part: [32][64][512]
#define OFF_WHH  (OFF_HNEW + 32*64*512)     // whh_part: [32][64][1536]
#define OFF_C0   (OFF_WHH + 32*64*1536)     // c0: [1536]
#define OFF_WCAT (OFF_C0 + 1536)            // Wcat: [576][4608] row-major
#define OFF_P1   (OFF_WCAT + 576*4608)      // P1: [4096][1536]
#define OFF_P2   (OFF_P1 + 4096*1536)       // P2: [4096][512]
// end = OFF_P2 + 4096*512 ≈ 71.6 MB

// sc1 (agent-scope) ops: bypass per-XCD L2, coherent at LLC. Used ONLY for
// (a) flag words and (b) the step-reused oc buffer. hTx reads are normal
// cached loads: buffers rotate per step (write-once-then-read addresses), so
// the first-touch L2 miss fetches the fresh LLC copy and peers hit L2 —
// measured in r7: sc1 staging saturated ~0.4-0.5 TB/s and was the bottleneck.
__device__ __forceinline__ float cohLoad(const float* p) {
  return __hip_atomic_load(p, __ATOMIC_RELAXED, __HIP_MEMORY_SCOPE_AGENT);
}
__device__ __forceinline__ void cohStore(float* p, float v) {
  __hip_atomic_store(p, v, __ATOMIC_RELAXED, __HIP_MEMORY_SCOPE_AGENT);
}
__device__ __forceinline__ int cohLoadI(const int* p) {
  return __hip_atomic_load(p, __ATOMIC_RELAXED, __HIP_MEMORY_SCOPE_AGENT);
}
__device__ __forceinline__ void cohStoreI(int* p, int v) {
  __hip_atomic_store(p, v, __ATOMIC_RELAXED, __HIP_MEMORY_SCOPE_AGENT);
}

// ---------------------------------------------------------------------------
// Generic tiled fp32 GEMM (pre-pass only)
// ---------------------------------------------------------------------------
__global__ __launch_bounds__(256) void gemm_f32(
    const float* __restrict__ A, const float* __restrict__ B,
    const float* __restrict__ bias, float* __restrict__ C,
    int M, int N, int K, int lda, int ldb, int ldc)
{
  __shared__ float As[16][132];
  __shared__ float Bs[16][64];
  const int bm = blockIdx.x * 128, bn = blockIdx.y * 64;
  const int tid = threadIdx.x;
  const int tx = tid & 15, ty = tid >> 4;
  float acc[8][4];
  #pragma unroll
  for (int i = 0; i < 8; ++i)
    #pragma unroll
    for (int j = 0; j < 4; ++j) acc[i][j] = 0.f;

  for (int kt = 0; kt < K; kt += 16) {
    #pragma unroll
    for (int i = 0; i < 2; ++i) {
      int li = tid + i*256;
      int r = li >> 2, q = li & 3;
      float4 a4 = *(const float4*)(A + (size_t)(bm + r)*lda + kt + q*4);
      As[q*4+0][r] = a4.x; As[q*4+1][r] = a4.y;
      As[q*4+2][r] = a4.z; As[q*4+3][r] = a4.w;
    }
    {
      int k = tid >> 4, nq = tid & 15;
      *(float4*)(&Bs[k][nq*4]) = *(const float4*)(B + (size_t)(kt + k)*ldb + bn + nq*4);
    }
    __syncthreads();
    #pragma unroll
    for (int kk = 0; kk < 16; ++kk) {
      float av[8], bv[4];
      *(float4*)(av)   = *(const float4*)(&As[kk][ty*8]);
      *(float4*)(av+4) = *(const float4*)(&As[kk][ty*8+4]);
      *(float4*)(bv)   = *(const float4*)(&Bs[kk][tx*4]);
      #pragma unroll
      for (int i = 0; i < 8; ++i)
        #pragma unroll
        for (int j = 0; j < 4; ++j) acc[i][j] += av[i]*bv[j];
    }
    __syncthreads();
  }
  #pragma unroll
  for (int i = 0; i < 8; ++i) {
    int m = bm + ty*8 + i;
    #pragma unroll
    for (int j = 0; j < 4; ++j) {
      int n = bn + tx*4 + j;
      float v = acc[i][j];
      if (bias) v += bias[n];
      C[(size_t)m*ldc + n] = v;
    }
  }
}

// ---------------------------------------------------------------------------
// Setup: Wcat (row-major [576][4608]) static parts + c0.
// ---------------------------------------------------------------------------
__global__ __launch_bounds__(512) void setup_kernel(
    const float* __restrict__ W_hm, const float* __restrict__ fc2_w,
    const float* __restrict__ W_um, const float* __restrict__ W_hh,
    const float* __restrict__ bias, const float* __restrict__ fc2_b,
    float* __restrict__ Wcat, float* __restrict__ c0)
{
  const int idx = blockIdx.x * 512 + threadIdx.x;
  if (idx < 512*1536) {                       // rows 0:512, cols 0:1536
    int k = idx / 1536, c = idx % 1536;
    float v;
    if (c < 512)       v = W_hm[k*512 + c];
    else if (c < 1024) v = fc2_w[k*512 + (c-512)];
    else               v = fc2_w[(size_t)(512+k)*512 + (c-1024)];
    Wcat[(size_t)k*4608 + c] = v;
    return;
  }
  int i = idx - 512*1536;
  if (i < 64*4608) {                          // rows 512:576, all cols
    int k2 = i / 4608, c = i % 4608;
    Wcat[(size_t)(512+k2)*4608 + c] = (c < 512) ? W_um[k2*512 + c] : 0.f;
    return;
  }
  i -= 64*4608;
  if (i < 1536) {                             // c0 = fc2_b@W_hh + bias_hh
    float s = bias[1536 + i];
    for (int m = 0; m < 512; ++m) s += fc2_b[m] * W_hh[(size_t)m*1536 + i];
    c0[i] = s;
  }
}

// ---------------------------------------------------------------------------
// Persistent scan. Blocks 0..31: BC (batch). Blocks 32..223: GEMM.
// GEMM block g=cg*2+bg: cols [cg*48, cg*48+48), batches [bg*16, bg*16+16).
// Thread tile: (kseg8 x col16 x bq4): 3 cols x 4 batches, K-seg of 72.
// Cross-block signals: plain sc1 stores to per-block flag words. hx staging:
// NORMAL cached loads (rotating buffers -> first-touch fresh; L2 broadcast).
// ---------------------------------------------------------------------------
__global__ __launch_bounds__(NTHR, 1) void persist_kernel(
    const float* __restrict__ P1, const float* __restrict__ P2,
    const float* __restrict__ Wcat, float* __restrict__ oc,
    float* __restrict__ hTx_all, float* __restrict__ hnew_part,
    float* __restrict__ whh_part, const float* __restrict__ c0,
    const float* __restrict__ fc1_w, const float* __restrict__ fc1_b,
    const float* __restrict__ fc2_b, const float* __restrict__ u_noise,
    const int* __restrict__ length, const float* __restrict__ fc_w,
    const float* __restrict__ fc_b, float* __restrict__ out,
    int* __restrict__ bar)
{
  __shared__ float smem[15424];    // GEMM: hxs[9216] + red[8*776]; BC: scratch
  const int bid = blockIdx.x;
  const int tid = threadIdx.x;

  if (bid >= 32) {
    // ================= GEMM block =================
    const int gb  = bid - 32;            // 0..191
    const int cg  = gb >> 1;             // 0..95
    const int bg  = gb & 1;              // batch half
    const int colbase = cg * 48;
    const int s   = tid >> 6;            // K-seg 0..7 (72 rows)
    const int c   = (tid >> 2) & 15;     // col-triple 0..15
    const int bq  = tid & 3;             // batch-quad 0..3
    const int kbase = s * 72;
    float* hxs = smem;                   // [576][16] (this batch-half)
    float* red = smem + 9216;            // [8][776] (768 used + pad)

    for (int t = 0; t < 128; ++t) {
      // wait for my 16 batches' h(t)  (flags: sc1, always fresh)
      if (tid < 16) {
        while (cohLoadI(&bar[(bg*16 + tid)*32]) < t) __builtin_amdgcn_s_sleep(1);
      }
      __syncthreads();
      // stage hx half: 9216 floats = 36 KB. NORMAL cached loads — rotating
      // buffer means these lines were never read before on this XCD; first
      // miss pulls the fresh LLC copy, peer blocks on the XCD hit L2.
      const float* hsrc = hTx_all + (size_t)t*HTXS + bg*9216;
      for (int i = tid; i < 2304; i += NTHR)
        *(float4*)(hxs + i*4) = *(const float4*)(hsrc + i*4);
      __syncthreads();
      // 3 cols x 4 batches register tile over K-seg of 72
      float acc[4][3];
      #pragma unroll
      for (int bi = 0; bi < 4; ++bi)
        #pragma unroll
        for (int cj = 0; cj < 3; ++cj) acc[bi][cj] = 0.f;
      const float* wp = Wcat + (size_t)kbase*4608 + colbase + c*3;
      const float* hp = hxs + kbase*16 + bq*4;
      #pragma unroll 4
      for (int kk = 0; kk < 72; ++kk) {
        float4 h4 = *(const float4*)(hp); hp += 16;
        float w0 = wp[0], w1 = wp[1], w2 = wp[2]; wp += 4608;
        acc[0][0] += h4.x*w0; acc[0][1] += h4.x*w1; acc[0][2] += h4.x*w2;
        acc[1][0] += h4.y*w0; acc[1][1] += h4.y*w1; acc[1][2] += h4.y*w2;
        acc[2][0] += h4.z*w0; acc[2][1] += h4.z*w1; acc[2][2] += h4.z*w2;
        acc[3][0] += h4.w*w0; acc[3][1] += h4.w*w1; acc[3][2] += h4.w*w2;
      }
      // write K-seg partials
      {
        float* rp = red + s*776 + (bq*4)*48 + c*3;
        #pragma unroll
        for (int bi = 0; bi < 4; ++bi) {
          rp[bi*48 + 0] = acc[bi][0];
          rp[bi*48 + 1] = acc[bi][1];
          rp[bi*48 + 2] = acc[bi][2];
        }
      }
      __syncthreads();
      // 8-seg reduce + sc1 store to oc (step-reused buffer -> must be sc1)
      for (int i = tid; i < 768; i += NTHR) {
        float ssum = 0.f;
        #pragma unroll
        for (int w = 0; w < 8; ++w) ssum += red[w*776 + i];
        int b16 = i / 48, cc = i - b16*48;
        cohStore(&oc[(size_t)(bg*16 + b16)*4608 + colbase + cc], ssum);
      }
      __syncthreads();                   // drain sc1 stores (vmcnt 0)
      if (tid == 0) cohStoreI(&bar[1024 + gb*32], t + 1);
    }
  } else {
    // ================= BC block: batch b =================
    const int b = bid;
    const int lenb = length[b];
    float hcur = 0.f;
    float usage_r = -99999.f;            // valid for tid<64
    int jprev = 0;                       // thread-0 only
    int* flg = (int*)(smem + 1100);
    const float c0r = c0[tid], c0z = c0[512 + tid], c0n = c0[1024 + tid];
    const float fc2bv = fc2_b[tid];
    const float f1b = (tid < 64) ? fc1_b[tid] : 0.f;
    const int n_ = tid & 63, kg_ = tid >> 6;
    const float* fw = fc1_w + (size_t)kg_*64*64 + n_;

    for (int t = 0; t < 128; ++t) {
      const int t32b = t*32 + b;
      // prefetch step inputs (independent of flags)
      const float* p1p = P1 + (size_t)t32b*1536;
      float p1r = p1p[tid], p1z = p1p[512 + tid], p1n = p1p[1024 + tid];
      float p2v = P2[(size_t)t32b*512 + tid];
      float uval = (tid < 64) ? u_noise[(size_t)t32b*64 + tid] : 0.f;
      // ---- wait EARLY blocks (cols 0:1536): wflag[0..63] ----
      if (tid < 64) {
        while (cohLoadI(&bar[1024 + tid*32]) < t + 1) __builtin_amdgcn_s_sleep(1);
      }
      __syncthreads();
      const float* ocb = oc + (size_t)b*4608;
      float oct = cohLoad(ocb + tid);
      float vA  = cohLoad(ocb + 512  + tid);
      float vB  = cohLoad(ocb + 1024 + tid);
      smem[tid] = tanhf(p2v + oct);      // th
      __syncthreads();
      {                                  // fc1 partial dots
        float sdot = 0.f;
        #pragma unroll 8
        for (int k = 0; k < 64; ++k) sdot += smem[kg_*64 + k] * fw[(size_t)k*64];
        smem[512 + tid] = sdot;
      }
      __syncthreads();
      if (tid < 64) {                    // logits + Gumbel + wave argmax
        float l = f1b;
        #pragma unroll
        for (int kg = 0; kg < 8; ++kg) l += smem[512 + kg*64 + tid];
        l += -logf(1e-20f - logf(1e-20f + uval));
        float best = l; int idx = tid;
        #pragma unroll
        for (int off = 32; off >= 1; off >>= 1) {
          float ob = __shfl_xor(best, off);
          int   oi = __shfl_xor(idx,  off);
          if (ob > best || (ob == best && oi < idx)) { best = ob; idx = oi; }
        }
        if (tid == 0) {
          flg[0] = idx;
          flg[1] = (t < 64) ? t : jprev;
          jprev = idx;
        }
      }
      // ---- wait LATE blocks (cols 1536:4608): wflag[64..191] ----
      if (tid < 128) {
        while (cohLoadI(&bar[1024 + (64 + tid)*32]) < t + 1) __builtin_amdgcn_s_sleep(1);
      }
      __syncthreads();
      const int jj = flg[0], ss = flg[1];
      float vAW0 = cohLoad(ocb + 1536 + tid);
      float vAW1 = cohLoad(ocb + 2048 + tid);
      float vAW2 = cohLoad(ocb + 2560 + tid);
      float vBW0 = cohLoad(ocb + 3072 + tid);
      float vBW1 = cohLoad(ocb + 3584 + tid);
      float vBW2 = cohLoad(ocb + 4096 + tid);
      float hnp, w0, w1, w2;
      if (jj == ss) { hnp = vA; w0 = vAW0; w1 = vAW1; w2 = vAW2; }
      else {
        hnp = hnew_part[(size_t)(b*64 + jj)*512 + tid];
        const float* wpp = whh_part + (size_t)(b*64 + jj)*1536;
        w0 = wpp[tid]; w1 = wpp[512 + tid]; w2 = wpp[1024 + tid];
      }
      float h_new = hnp + vB + fc2bv;
      float wh_r = w0 + vBW0 + c0r;
      float wh_z = w1 + vBW1 + c0z;
      float wh_n = w2 + vBW2 + c0n;
      float r  = 1.f / (1.f + expf(-(p1r + wh_r)));
      float z  = 1.f / (1.f + expf(-(p1z + wh_z)));
      float nn = tanhf(p1n + r*wh_n);
      float h1 = (1.f - z)*nn + z*h_new;
      if (t >= lenb) h1 = hcur;
      hcur = h1;
      // publish h(t+1)+lu into half (b>>4), layout [576][16] (sc1 -> LLC)
      float* hw = hTx_all + (size_t)(t + 1)*HTXS + (b >> 4)*9216;
      cohStore(&hw[tid*16 + (b & 15)], h1);
      if (tid < 64) {
        float un = (usage_r - 1.f) * (tid == jj ? 0.f : 1.f);
        usage_r = un;
        cohStore(&hw[(512 + tid)*16 + (b & 15)], 1.f / (1.f + expf(-un)));
      }
      smem[tid] = h1;                    // for out projection below
      __syncthreads();                   // drain sc1 stores
      if (tid == 0) cohStoreI(&bar[b*32], t + 1);
      // ---- off critical path: slot caches + output projection ----
      hnew_part[(size_t)(b*64 + ss)*512 + tid] = vA;
      float* wps = whh_part + (size_t)(b*64 + ss)*1536;
      wps[tid] = vAW0; wps[512 + tid] = vAW1; wps[1024 + tid] = vAW2;
      {
        int a = tid & 31, jg = tid >> 5;
        float sp = 0.f;
        #pragma unroll 8
        for (int jx = 0; jx < 32; ++jx)
          sp += smem[jg*32 + jx] * fc_w[(size_t)(jg*32 + jx)*32 + a];
        smem[512 + tid] = sp;
      }
      __syncthreads();
      if (tid < 32) {
        float s2 = fc_b[tid];
        #pragma unroll
        for (int jg = 0; jg < 16; ++jg) s2 += smem[512 + jg*32 + tid];
        out[(size_t)t32b*32 + tid] = s2;
      }
    }
  }
}

// ---------------------------------------------------------------------------
extern "C" void kernel_launch(void* const* d_in, const int* in_sizes, int n_in,
                              void* d_out, int out_size, void* d_ws, size_t ws_size,
                              hipStream_t stream)
{
  const float* x      = (const float*)d_in[0];
  const int*   length = (const int*)  d_in[1];
  const float* u_nois = (const float*)d_in[2];
  const float* W_ih   = (const float*)d_in[3];
  const float* W_hh   = (const float*)d_in[4];
  const float* bias   = (const float*)d_in[5];
  const float* W_im   = (const float*)d_in[6];
  const float* W_hm   = (const float*)d_in[7];
  const float* W_um   = (const float*)d_in[8];
  const float* fc1_w  = (const float*)d_in[9];
  const float* fc1_b  = (const float*)d_in[10];
  const float* fc2_w  = (const float*)d_in[11];
  const float* fc2_b  = (const float*)d_in[12];
  const float* fc_w   = (const float*)d_in[13];
  const float* fc_b   = (const float*)d_in[14];
  float* out = (float*)d_out;

  float* ws   = (float*)d_ws;
  int*   bar  = (int*)d_ws;
  float* hTx  = ws + OFF_HTX;
  float* oc   = ws + OFF_OC;
  float* hnew = ws + OFF_HNEW;
  float* whh  = ws + OFF_WHH;
  float* c0   = ws + OFF_C0;
  float* Wcat = ws + OFF_WCAT;
  float* P1   = ws + OFF_P1;
  float* P2   = ws + OFF_P2;

  // zero: flag words + hTx buffer 0 (h=0, lu=0); slot caches (mem=0)
  hipMemsetAsync(d_ws, 0, (size_t)(OFF_HTX + HTXS) * sizeof(float), stream);
  hipMemsetAsync(hnew, 0, (size_t)(32*64*512 + 32*64*1536) * sizeof(float), stream);

  setup_kernel<<<2115, 512, 0, stream>>>(W_hm, fc2_w, W_um, W_hh, bias, fc2_b,
                                         Wcat, c0);

  // M_A = fc2_A@W_hh -> Wcat cols 1536:3072 ; M_B = fc2_B@W_hh -> 3072:4608
  { dim3 g(4, 24);
    gemm_f32<<<g, 256, 0, stream>>>(fc2_w,                   W_hh, nullptr, Wcat + 1536,
                                    512, 1536, 512, 512, 1536, 4608);
    gemm_f32<<<g, 256, 0, stream>>>(fc2_w + (size_t)512*512, W_hh, nullptr, Wcat + 3072,
                                    512, 1536, 512, 512, 1536, 4608); }
  // P1 = x@W_ih + bias_ih ; P2 = x@W_im
  { dim3 g(32, 24);
    gemm_f32<<<g, 256, 0, stream>>>(x, W_ih, bias, P1, 4096, 1536, 512, 512, 1536, 1536); }
  { dim3 g(32, 8);
    gemm_f32<<<g, 256, 0, stream>>>(x, W_im, nullptr, P2, 4096, 512, 512, 512, 512, 512); }

  persist_kernel<<<NBLK, NTHR, 0, stream>>>(P1, P2, Wcat, oc, hTx, hnew, whh,
                                            c0, fc1_w, fc1_b, fc2_b, u_nois,
                                            length, fc_w, fc_b, out, bar);
}